// Round 2
// baseline (1459.031 us; speedup 1.0000x reference)
//
#include <hip/hip_runtime.h>
#include <hip/hip_bf16.h>

typedef __attribute__((ext_vector_type(8))) short bf16x8;
typedef __attribute__((ext_vector_type(4))) float f32x4;
typedef __attribute__((ext_vector_type(2))) unsigned int u32x2;

constexpr int NB = 2048;
constexpr int NE = 30, NN = 8, NAll = 38;
constexpr int BAS = 32, KD = 64, ED = 128, HK = 45, HO = 91, LNUM = 3;

#define MFMA(a, b, c) __builtin_amdgcn_mfma_f32_16x16x32_bf16((a), (b), (c), 0, 0, 0)

// hardware packed f32->bf16 (RNE), 1 instr per 2 values (guide T12 recipe)
__device__ __forceinline__ unsigned cvtpk(float a, float b) {
    unsigned r;
    asm("v_cvt_pk_bf16_f32 %0, %1, %2" : "=v"(r) : "v"(a), "v"(b));
    return r;
}
__device__ __forceinline__ unsigned short f2b(float v) {
    return (unsigned short)cvtpk(v, v);
}
__device__ __forceinline__ bf16x8 cvt8(f32x4 lo, f32x4 hi) {
    union { unsigned u[4]; bf16x8 v; } r;
    r.u[0] = cvtpk(lo[0], lo[1]);
    r.u[1] = cvtpk(lo[2], lo[3]);
    r.u[2] = cvtpk(hi[0], hi[1]);
    r.u[3] = cvtpk(hi[2], hi[3]);
    return r.v;
}
__device__ __forceinline__ float ssp(float x) {
    float e = __expf(-fabsf(x));
    return fmaxf(x, 0.f) + __logf(1.f + e) - 0.69314718055994530942f;
}
// XOR-swizzled element index; writers/readers agree. S = elems/row (pow2 mult of 8).
__device__ __forceinline__ int swzi(int row, int col, int S) {
    int mask = (S >> 3) - 1;
    int blk = ((col >> 3) ^ row) & mask;
    return row * S + (blk << 3) + (col & 7);
}
__device__ __forceinline__ bf16x8 ldfrag(const unsigned short* p, int S, int row, int col) {
    int mask = (S >> 3) - 1;
    int blk = ((col >> 3) ^ row) & mask;
    return *(const bf16x8*)(p + row * S + (blk << 3));
}
__device__ __forceinline__ f32x4 ldf4s(const float* p, int S, int row, int col) {
    int mask = (S >> 3) - 1;
    int blk = ((col >> 3) ^ row) & mask;
    return *(const f32x4*)(p + row * S + (blk << 3) + (col & 7));
}

__global__ __launch_bounds__(256, 5) void schnet_mfma(
    const float* __restrict__ dists,
    const float* __restrict__ emb_e,
    const float* __restrict__ emb_n,
    const float* __restrict__ kw1, const float* __restrict__ kb1,
    const float* __restrict__ kw2, const float* __restrict__ kb2,
    const float* __restrict__ ew,
    const float* __restrict__ ow1, const float* __restrict__ ob1,
    const float* __restrict__ ow2, const float* __restrict__ ob2,
    float* __restrict__ out)
{
    // 29.75 KB LDS -> 5 blocks/CU (with VGPR cap 102 via launch_bounds(256,5))
    __shared__ __align__(16) unsigned char smem[30464];
    float* zsb  = (float*)smem;                             // [38][64] f32 (30..37 = nuc)
    float* stot = (float*)(smem + 9728);                    // [64] col sums of zsb
    unsigned short* w2tA = (unsigned short*)(smem + 9984);  // [64 c][32 h0..31]
    unsigned short* w2tB = (unsigned short*)(smem + 14080); // [64 c][16 h32..47]
    unsigned char* U = smem + 16128;                        // 14336 B phase union

    const int b = blockIdx.x;
    const int t = threadIdx.x;
    const int lane = t & 63, wv = t >> 6;
    const int q = lane >> 4, cc = lane & 15;
    const float* db_b = dists + (size_t)b * NE * NAll * BAS;
    float* xsg = out + (size_t)b * NE * ED;   // xs state lives in output buffer

    const f32x4 zz = {0.f, 0.f, 0.f, 0.f};
    const bf16x8 zb = {0, 0, 0, 0, 0, 0, 0, 0};

    for (int o = t; o < NE * ED; o += 256) xsg[o] = emb_e[o];
    for (int o = t; o < NN * KD; o += 256) zsb[NE * KD + o] = emb_n[o];
    __syncthreads();

    for (int l = 0; l < LNUM; ++l) {
        const float* w1g = kw1 + l * BAS * HK;
        const float* b1g = kb1 + l * HK;
        const float* w2g = kw2 + l * HK * KD;
        const float* b2g = kb2 + l * KD;
        const float* weg = ew  + l * ED * KD;
        const float* o1g = ow1 + l * KD * HO;
        const float* g1g = ob1 + l * HO;
        const float* o2g = ow2 + l * HO * ED;
        const float* g2g = ob2 + l * ED;

        // ===== zs phase: zsb[0:30] = xs @ ew  (wet staged in two 8KB k-halves) =====
        {
            unsigned short* wet = (unsigned short*)U;   // [64 c][64 e-half]
            f32x4 zacc[2] = {zz, zz};
            #pragma unroll
            for (int kh = 0; kh < 2; ++kh) {
                for (int o = t; o < 64 * 64; o += 256) {
                    int c2 = o & 63, e2 = o >> 6;       // coalesced over c
                    wet[swzi(c2, e2, 64)] = f2b(weg[(kh * 64 + e2) * KD + c2]);
                }
                if (kh == 0) {  // stage pair-phase W2 concurrently (own region)
                    for (int o = t; o < 64 * 32; o += 256) {
                        int c2 = o & 63, h = o >> 6;
                        w2tA[swzi(c2, h, 32)] = f2b(w2g[h * KD + c2]);
                    }
                    for (int o = t; o < 64 * 16; o += 256) {
                        int c2 = o & 63, h2 = o >> 6, h = 32 + h2;
                        w2tB[swzi(c2, h2, 16)] = f2b((h < HK) ? w2g[h * KD + c2] : 0.f);
                    }
                }
                __syncthreads();
                #pragma unroll
                for (int ksl = 0; ksl < 2; ++ksl) {
                    bf16x8 wf = ldfrag(wet, 64, wv * 16 + cc, ksl * 32 + q * 8);
                    #pragma unroll
                    for (int mt = 0; mt < 2; ++mt) {
                        int ra = mt * 16 + cc; if (ra > NE - 1) ra = NE - 1;  // clamp; rows 30/31 garbage, masked at store
                        const float* xp = xsg + ra * ED + kh * 64 + ksl * 32 + q * 8;
                        zacc[mt] = MFMA(cvt8(*(const f32x4*)xp, *(const f32x4*)(xp + 4)), wf, zacc[mt]);
                    }
                }
                if (kh == 1) {
                    #pragma unroll
                    for (int mt = 0; mt < 2; ++mt)
                        #pragma unroll
                        for (int r = 0; r < 4; ++r) {
                            int rr = mt * 16 + q * 4 + r;
                            if (rr < NE) zsb[rr * 64 + wv * 16 + cc] = zacc[mt][r];  // keep nuc rows intact
                        }
                }
                __syncthreads();
            }
        }

        // stot (tiny serial) — visibility guaranteed by pair-end barriers before use
        if (t < 64) {
            float s = 0.f;
            for (int jj = 0; jj < NAll; ++jj) s += zsb[jj * 64 + t];
            stot[t] = s;
        }

        // w1/b1 fragments direct from global (L2-hot weights), once per layer
        bf16x8 w1f[3]; f32x4 b1q[3];
        #pragma unroll
        for (int nt = 0; nt < 3; ++nt) {
            int h = nt * 16 + cc;
            if (h < HK) {
                f32x4 lo, hi;
                #pragma unroll
                for (int jj = 0; jj < 4; ++jj) lo[jj] = w1g[(q * 8 + jj) * HK + h];
                #pragma unroll
                for (int jj = 0; jj < 4; ++jj) hi[jj] = w1g[(q * 8 + 4 + jj) * HK + h];
                w1f[nt] = cvt8(lo, hi);
            } else w1f[nt] = zb;
            b1q[nt] = *(const f32x4*)(b1g + nt * 16 + q * 4);  // <=12B over-read on last layer: pad values hit zeroed W2 cols
        }

        // ===== pair phase: per-wave private, barrier-free j loop ==================
        unsigned short* HbA = (unsigned short*)(U + wv * 3072);  // [32 i][32 h]
        unsigned short* HbB = HbA + 1024;                        // [32 i][16 h]
        f32x4 mr[2][4];
        #pragma unroll
        for (int mt = 0; mt < 2; ++mt)
            #pragma unroll
            for (int nt = 0; nt < 4; ++nt) mr[mt][nt] = zz;

        auto pbody = [&](bool DIAG, int j) {
            int r1 = 16 + cc; if (r1 > NE - 1) r1 = NE - 1;      // clamp rows 30/31
            int j0 = DIAG ? cc : j;
            int j1 = DIAG ? r1 : j;
            const float* dp0 = db_b + (cc * NAll + j0) * BAS + q * 8;
            const float* dp1 = db_b + (r1 * NAll + j1) * BAS + q * 8;
            bf16x8 fa0 = cvt8(*(const f32x4*)dp0, *(const f32x4*)(dp0 + 4));
            bf16x8 fa1 = cvt8(*(const f32x4*)dp1, *(const f32x4*)(dp1 + 4));
            // GEMM1 swapped: mfma(W1^T, db^T) -> lane holds 4 consecutive h per row i
            #pragma unroll
            for (int nt = 0; nt < 3; ++nt) {
                f32x4 h0 = MFMA(w1f[nt], fa0, zz);
                f32x4 h1 = MFMA(w1f[nt], fa1, zz);
                u32x2 v0, v1;
                v0.x = cvtpk(ssp(h0[0] + b1q[nt][0]), ssp(h0[1] + b1q[nt][1]));
                v0.y = cvtpk(ssp(h0[2] + b1q[nt][2]), ssp(h0[3] + b1q[nt][3]));
                v1.x = cvtpk(ssp(h1[0] + b1q[nt][0]), ssp(h1[1] + b1q[nt][1]));
                v1.y = cvtpk(ssp(h1[2] + b1q[nt][2]), ssp(h1[3] + b1q[nt][3]));
                if (nt < 2) {
                    *(u32x2*)(HbA + swzi(cc,      nt * 16 + q * 4, 32)) = v0;
                    *(u32x2*)(HbA + swzi(16 + cc, nt * 16 + q * 4, 32)) = v1;
                } else {
                    *(u32x2*)(HbB + swzi(cc,      q * 4, 16)) = v0;
                    *(u32x2*)(HbB + swzi(16 + cc, q * 4, 16)) = v1;
                }
            }
            float zv[4];
            if (!DIAG) {
                #pragma unroll
                for (int nt = 0; nt < 4; ++nt) zv[nt] = zsb[j * 64 + nt * 16 + cc];
            }
            bf16x8 afA[2], afB[2];
            #pragma unroll
            for (int mt = 0; mt < 2; ++mt) {
                afA[mt] = ldfrag(HbA, 32, mt * 16 + cc, q * 8);
                afB[mt] = ldfrag(HbB, 16, mt * 16 + cc, q * 8);
                if (q >= 2) afB[mt] = zb;   // k-lanes h>=48 must be zero
            }
            #pragma unroll
            for (int nt = 0; nt < 4; ++nt) {
                bf16x8 wA = ldfrag(w2tA, 32, nt * 16 + cc, q * 8);
                bf16x8 wB = ldfrag(w2tB, 16, nt * 16 + cc, q * 8);  // q>=2 reads alias, x afB=0
                #pragma unroll
                for (int mt = 0; mt < 2; ++mt) {
                    f32x4 a2 = MFMA(afA[mt], wA, zz);
                    a2 = MFMA(afB[mt], wB, a2);
                    #pragma unroll
                    for (int r = 0; r < 4; ++r) {
                        if (DIAG)
                            mr[mt][nt][r] -= a2[r] * zsb[(mt * 16 + q * 4 + r) * 64 + nt * 16 + cc];
                        else
                            mr[mt][nt][r] += a2[r] * zv[nt];  // unconditional; j==i removed by diag pass
                    }
                }
            }
        };

        for (int j = wv; j < NAll; j += 4) pbody(false, j);
        if (wv == 0) pbody(true, 0);   // subtract W(i,i) * zs_i
        __syncthreads();               // Hb use done; U -> msgf

        // ===== msg reduction: zero + ds_add_f32 into one 8KB buffer ===============
        float* msgf = (float*)U;       // [32][64] f32, swizzled
        #pragma unroll
        for (int o = 0; o < 2; ++o) *(f32x4*)(msgf + t * 4 + o * 1024) = zz;
        __syncthreads();
        if (wv == 0) {                 // factored b2 term: + b2 * (stot - zs_i)
            #pragma unroll
            for (int nt = 0; nt < 4; ++nt) {
                int col = nt * 16 + cc;
                float b2v = b2g[col];
                float st = stot[col];
                #pragma unroll
                for (int mt = 0; mt < 2; ++mt)
                    #pragma unroll
                    for (int r = 0; r < 4; ++r)
                        mr[mt][nt][r] += b2v * (st - zsb[(mt * 16 + q * 4 + r) * 64 + col]);
            }
        }
        #pragma unroll
        for (int mt = 0; mt < 2; ++mt)
            #pragma unroll
            for (int nt = 0; nt < 4; ++nt)
                #pragma unroll
                for (int r = 0; r < 4; ++r)
                    atomicAdd(msgf + swzi(mt * 16 + q * 4 + r, nt * 16 + cc, 64), mr[mt][nt][r]);
        __syncthreads();

        // ===== out phase ==========================================================
        {
            unsigned short* o1t  = (unsigned short*)(U + 8192);  // [96 h][32 m-half]
            unsigned short* hobA = (unsigned short*)U;           // [32 i][64 h]
            unsigned short* hobB = hobA + 2048;                  // [32 i][32 h]
            const int ih = wv & 1;
            bf16x8 afo[2];
            #pragma unroll
            for (int ks = 0; ks < 2; ++ks)
                afo[ks] = cvt8(ldf4s(msgf, 64, ih * 16 + cc, ks * 32 + q * 8),
                               ldf4s(msgf, 64, ih * 16 + cc, ks * 32 + q * 8 + 4));
            f32x4 oa[3] = {zz, zz, zz};
            #pragma unroll
            for (int kh = 0; kh < 2; ++kh) {
                for (int o = t; o < 96 * 32; o += 256) {
                    int h = o % 96, m = o / 96;                  // coalesced over h
                    o1t[swzi(h, m, 32)] = f2b((h < HO) ? o1g[(kh * 32 + m) * HO + h] : 0.f);
                }
                __syncthreads();
                #pragma unroll
                for (int s = 0; s < 3; ++s) {
                    int ht = (wv >> 1) + 2 * s;
                    oa[s] = MFMA(ldfrag(o1t, 32, ht * 16 + cc, q * 8), afo[kh], oa[s]);
                }
                if (kh == 1) {   // ssp + b64 hob stores (overwrites msgf; afo read long ago)
                    #pragma unroll
                    for (int s = 0; s < 3; ++s) {
                        int ht = (wv >> 1) + 2 * s;
                        f32x4 g1q = *(const f32x4*)(g1g + ht * 16 + q * 4);  // <=20B over-read last layer; pads hit zero W cols
                        u32x2 hv;
                        hv.x = cvtpk(ssp(oa[s][0] + g1q[0]), ssp(oa[s][1] + g1q[1]));
                        hv.y = cvtpk(ssp(oa[s][2] + g1q[2]), ssp(oa[s][3] + g1q[3]));
                        int i = ih * 16 + cc;
                        if (ht < 4) *(u32x2*)(hobA + swzi(i, ht * 16 + q * 4, 64)) = hv;
                        else        *(u32x2*)(hobB + swzi(i, (ht - 4) * 16 + q * 4, 32)) = hv;
                    }
                }
                __syncthreads();
            }
            // GEMM o2 per ED half; o2t staged in (h0..63) then (h64..95) sub-stages
            unsigned short* o2t = (unsigned short*)(U + 6144);
            #pragma unroll
            for (int ph = 0; ph < 2; ++ph) {
                for (int o = t; o < 64 * 64; o += 256) {
                    int e = o & 63, h = o >> 6;                  // coalesced over e
                    o2t[swzi(e, h, 64)] = f2b(o2g[h * ED + ph * 64 + e]);
                }
                __syncthreads();
                f32x4 acc2[2];
                {
                    bf16x8 bf0 = ldfrag(o2t, 64, wv * 16 + cc, q * 8);
                    bf16x8 bf1 = ldfrag(o2t, 64, wv * 16 + cc, 32 + q * 8);
                    #pragma unroll
                    for (int mt = 0; mt < 2; ++mt) {
                        acc2[mt] = MFMA(ldfrag(hobA, 64, mt * 16 + cc, q * 8), bf0, zz);
                        acc2[mt] = MFMA(ldfrag(hobA, 64, mt * 16 + cc, 32 + q * 8), bf1, acc2[mt]);
                    }
                }
                __syncthreads();
                for (int o = t; o < 64 * 32; o += 256) {
                    int e = o & 63, h2 = o >> 6, h = 64 + h2;
                    o2t[swzi(e, h2, 32)] = f2b((h < HO) ? o2g[h * ED + ph * 64 + e] : 0.f);
                }
                __syncthreads();
                {
                    bf16x8 bf2 = ldfrag(o2t, 32, wv * 16 + cc, q * 8);
                    float g2v = g2g[ph * 64 + wv * 16 + cc];
                    #pragma unroll
                    for (int mt = 0; mt < 2; ++mt) {
                        acc2[mt] = MFMA(ldfrag(hobB, 32, mt * 16 + cc, q * 8), bf2, acc2[mt]);
                        #pragma unroll
                        for (int r = 0; r < 4; ++r) {
                            int i = mt * 16 + q * 4 + r;
                            if (i < NE) xsg[i * ED + ph * 64 + wv * 16 + cc] += acc2[mt][r] + g2v;
                        }
                    }
                }
                __syncthreads();
            }
        }
    }
    // xs accumulated directly in `out`
}

extern "C" void kernel_launch(void* const* d_in, const int* in_sizes, int n_in,
                              void* d_out, int out_size, void* d_ws, size_t ws_size,
                              hipStream_t stream) {
    const float* dists = (const float*)d_in[0];
    const float* emb_e = (const float*)d_in[1];
    const float* emb_n = (const float*)d_in[2];
    const float* kw1   = (const float*)d_in[3];
    const float* kb1   = (const float*)d_in[4];
    const float* kw2   = (const float*)d_in[5];
    const float* kb2   = (const float*)d_in[6];
    const float* ew    = (const float*)d_in[7];
    const float* ow1   = (const float*)d_in[8];
    const float* ob1   = (const float*)d_in[9];
    const float* ow2   = (const float*)d_in[10];
    const float* ob2   = (const float*)d_in[11];
    float* out = (float*)d_out;

    schnet_mfma<<<NB, 256, 0, stream>>>(dists, emb_e, emb_n, kw1, kb1, kw2, kb2,
                                        ew, ow1, ob1, ow2, ob2, out);
}